// Round 1
// baseline (148.190 us; speedup 1.0000x reference)
//
#include <hip/hip_runtime.h>
#include <hip/hip_fp16.h>

#define Bq 16
#define Nq 2048
#define Sq 4096
#define Dq 128
#define VOCABq 50257
#define NNZq 1048576
#define ROWS (Bq * Nq)   // 32768
#define NBIN 2048        // coarse bins
#define RPB 16           // rows per bin
#define BCAP 768         // bin capacity (mean 512, +11 sigma)
#define OVF_MAX 65536
#define BTPB 1024        // fused kernel threads
#define BEPT 4           // bin entries/thread
#define NBBIN 256        // bin blocks (NNZ / (BTPB*BEPT))
#define CAST_QPT 4       // cast quads per thread
#define CSTRIDE 16       // binCnt padding: 1 counter per 64B line

typedef unsigned long long u64;
typedef float vfloat4 __attribute__((ext_vector_type(4)));
typedef unsigned short vushort4 __attribute__((ext_vector_type(4)));
typedef unsigned short vushort8 __attribute__((ext_vector_type(8)));

// ---------- Fused pass A: [blocks 0..255] coarse-bin radix scatter
// ----------          + [blocks 256..648] emb fp32->fp16 cast (independent work,
//                       overlapped in HW instead of serialized on the stream) ----------
__global__ __launch_bounds__(BTPB) void cast_bin_kernel(
    const float* __restrict__ emb,         // [VOCAB,D] fp32
    unsigned short* __restrict__ emb16,    // [VOCAB,D] fp16 out
    const int* __restrict__ subnode_ids,   // [B,S]
    const int* __restrict__ mb,            // [NNZ]
    const int* __restrict__ mn,            // [NNZ]
    const int* __restrict__ ms,            // [NNZ]
    const float* __restrict__ mv,          // [NNZ]
    int* __restrict__ binCnt,              // [NBIN*CSTRIDE] (zeroed; 64B/counter)
    u64* __restrict__ binMem,              // [NBIN*BCAP] packed entries
    int* __restrict__ ovfn,                // overflow counter (zeroed)
    int* __restrict__ ovf)                 // overflow nz list
{
    __shared__ int hist[NBIN];
    __shared__ int base[NBIN];
    int t = threadIdx.x;

    if (blockIdx.x >= NBBIN) {
        // ---- cast part: linear stream, nontemporal stores ----
        const int NQUAD = (VOCABq * Dq) / 4;  // 1,608,224
        int b0 = (blockIdx.x - NBBIN) * (BTPB * CAST_QPT) + t;
        #pragma unroll
        for (int k = 0; k < CAST_QPT; k++) {
            int i = b0 + k * BTPB;
            if (i < NQUAD) {
                vfloat4 f = reinterpret_cast<const vfloat4*>(emb)[i];
                vushort4 h;
                h.x = __half_as_ushort(__float2half_rn(f.x));
                h.y = __half_as_ushort(__float2half_rn(f.y));
                h.z = __half_as_ushort(__float2half_rn(f.z));
                h.w = __half_as_ushort(__float2half_rn(f.w));
                __builtin_nontemporal_store(h, reinterpret_cast<vushort4*>(emb16) + i);
            }
        }
        return;
    }

    // ---- bin part: block-aggregated radix scatter ----
    for (int g = t; g < NBIN; g += BTPB) hist[g] = 0;
    __syncthreads();

    int blockBase = blockIdx.x * (BTPB * BEPT);
    int g[BEPT], rank[BEPT];
    u64 pk[BEPT];
    #pragma unroll
    for (int k = 0; k < BEPT; k++) {       // coalesced NT index loads + L2 token gather
        int i   = blockBase + k * BTPB + t;
        int b   = __builtin_nontemporal_load(mb + i);
        int row = b * Nq + __builtin_nontemporal_load(mn + i);
        int s   = __builtin_nontemporal_load(ms + i);
        float v = __builtin_nontemporal_load(mv + i);
        int tok = subnode_ids[b * Sq + s];
        g[k]  = row >> 4;                  // coarse bin (16 rows)
        pk[k] = ((u64)(unsigned)__float_as_int(v) << 32)
              | ((u64)(row & 15) << 16)
              | (unsigned)tok;             // tok < 65536 fits 16 bits
        rank[k] = atomicAdd(&hist[g[k]], 1);
    }
    __syncthreads();
    for (int gg = t; gg < NBIN; gg += BTPB) {
        int h = hist[gg];
        // padded counters: one per 64B cacheline -> 2048-line-parallel atomics
        base[gg] = h ? atomicAdd(&binCnt[gg * CSTRIDE], h) : 0;
    }
    __syncthreads();
    #pragma unroll
    for (int k = 0; k < BEPT; k++) {
        int p = base[g[k]] + rank[k];
        if (p < BCAP) {
            binMem[(size_t)g[k] * BCAP + p] = pk[k];
        } else {
            int o = atomicAdd(ovfn, 1);
            if (o < OVF_MAX) ovf[o] = blockBase + k * BTPB + t;
        }
    }
}

// ---------- Pass B: in-LDS sort by (token-quarter, row) + phased pool ----------
// One 256-thread block per bin (16 rows). Sort key = (tok>>14)<<4 | row_local:
// the block processes entries in 4 token-range phases (~3.2MB table slice,
// L2-resident across co-resident blocks). 16 groups of 16 lanes; group g owns
// row g (lane = 16B ushort8 slice); acc in fp32 regs; one NT 512B store/row.
// Rare overflow entries are folded in here (scan only if *ovfn > 0).
__global__ __launch_bounds__(256) void pool_kernel(
    const unsigned short* __restrict__ emb16,  // [VOCAB,D] fp16
    const int* __restrict__ binCnt,            // [NBIN*CSTRIDE]
    const u64* __restrict__ binMem,            // [NBIN*BCAP]
    const int* __restrict__ subnode_ids,
    const int* __restrict__ mb, const int* __restrict__ mn,
    const int* __restrict__ ms, const float* __restrict__ mv,
    const int* __restrict__ ovfn, const int* __restrict__ ovf,
    float* __restrict__ out)                   // [ROWS,D]
{
    __shared__ u64 ebuf[BCAP];           // 6 KB sorted entries
    __shared__ int hist[64];
    __shared__ int start[65];
    __shared__ int cursor[64];

    int t   = threadIdx.x;
    int bin = blockIdx.x;
    if (t < 64) hist[t] = 0;
    __syncthreads();

    int n = min(binCnt[bin * CSTRIDE], BCAP);
    const u64* bm = binMem + (size_t)bin * BCAP;

    // stage entries (<=3 per thread) + histogram 64 keys (NT: binMem read once)
    u64 myPk[3];
    int myKey[3], myCnt = 0;
    for (int e = t; e < n; e += 256) {
        u64 pk  = __builtin_nontemporal_load(bm + e);
        int tok = (int)(pk & 0xFFFF);
        int key = ((tok >> 14) << 4) | (int)((pk >> 16) & 15);
        myPk[myCnt] = pk; myKey[myCnt] = key; myCnt++;
        atomicAdd(&hist[key], 1);
    }
    __syncthreads();
    // exclusive prefix over 64 counters: threads 0..63 are wave 0
    if (t < 64) {
        int v = hist[t];
        #pragma unroll
        for (int d = 1; d < 64; d <<= 1) {
            int w = __shfl_up(v, d, 64);
            if (t >= d) v += w;
        }
        start[t + 1] = v;
        if (t == 0) start[0] = 0;
    }
    __syncthreads();
    if (t < 64) cursor[t] = start[t];
    __syncthreads();
    for (int k = 0; k < myCnt; k++) {
        int p = atomicAdd(&cursor[myKey[k]], 1);
        ebuf[p] = myPk[k];
    }
    __syncthreads();

    // pool: group g (16 lanes) owns row g; 4 token-quarter phases
    int g    = t >> 4;
    int lane = t & 15;
    vfloat4 a0 = {0.f, 0.f, 0.f, 0.f};
    vfloat4 a1 = {0.f, 0.f, 0.f, 0.f};
    #pragma unroll
    for (int q = 0; q < 4; q++) {
        int s0 = start[q * 16 + g], s1 = start[q * 16 + g + 1];
        int k = s0;
        for (; k + 8 <= s1; k += 8) {      // 8 independent 256B row-gathers in flight
            int   tk[8];
            float vv[8];
            #pragma unroll
            for (int u = 0; u < 8; u++) {
                u64 pk = ebuf[k + u];      // same addr within group -> broadcast
                tk[u] = (int)(pk & 0xFFFF);
                vv[u] = __int_as_float((int)(pk >> 32));
            }
            vushort8 e[8];
            #pragma unroll
            for (int u = 0; u < 8; u++)
                e[u] = reinterpret_cast<const vushort8*>(emb16 + (size_t)tk[u] * Dq)[lane];
            #pragma unroll
            for (int u = 0; u < 8; u++) {
                a0.x += __half2float(__ushort_as_half(e[u][0])) * vv[u];
                a0.y += __half2float(__ushort_as_half(e[u][1])) * vv[u];
                a0.z += __half2float(__ushort_as_half(e[u][2])) * vv[u];
                a0.w += __half2float(__ushort_as_half(e[u][3])) * vv[u];
                a1.x += __half2float(__ushort_as_half(e[u][4])) * vv[u];
                a1.y += __half2float(__ushort_as_half(e[u][5])) * vv[u];
                a1.z += __half2float(__ushort_as_half(e[u][6])) * vv[u];
                a1.w += __half2float(__ushort_as_half(e[u][7])) * vv[u];
            }
        }
        for (; k < s1; k++) {
            u64 pk = ebuf[k];
            int   tok = (int)(pk & 0xFFFF);
            float v   = __int_as_float((int)(pk >> 32));
            vushort8 e = reinterpret_cast<const vushort8*>(emb16 + (size_t)tok * Dq)[lane];
            a0.x += __half2float(__ushort_as_half(e[0])) * v;
            a0.y += __half2float(__ushort_as_half(e[1])) * v;
            a0.z += __half2float(__ushort_as_half(e[2])) * v;
            a0.w += __half2float(__ushort_as_half(e[3])) * v;
            a1.x += __half2float(__ushort_as_half(e[4])) * v;
            a1.y += __half2float(__ushort_as_half(e[5])) * v;
            a1.z += __half2float(__ushort_as_half(e[6])) * v;
            a1.w += __half2float(__ushort_as_half(e[7])) * v;
        }
    }

    // rare overflow fold-in (usually *ovfn == 0): accumulate before the store
    int nov = min(*ovfn, OVF_MAX);
    for (int e2 = 0; e2 < nov; e2++) {
        int i = ovf[e2];
        int b = mb[i];
        int row = b * Nq + mn[i];
        if ((row >> 4) != bin || (row & 15) != g) continue;
        int tok = subnode_ids[b * Sq + ms[i]];
        float v = mv[i];
        vushort8 e = reinterpret_cast<const vushort8*>(emb16 + (size_t)tok * Dq)[lane];
        a0.x += __half2float(__ushort_as_half(e[0])) * v;
        a0.y += __half2float(__ushort_as_half(e[1])) * v;
        a0.z += __half2float(__ushort_as_half(e[2])) * v;
        a0.w += __half2float(__ushort_as_half(e[3])) * v;
        a1.x += __half2float(__ushort_as_half(e[4])) * v;
        a1.y += __half2float(__ushort_as_half(e[5])) * v;
        a1.z += __half2float(__ushort_as_half(e[6])) * v;
        a1.w += __half2float(__ushort_as_half(e[7])) * v;
    }

    float* orow = out + ((size_t)bin * RPB + g) * Dq + lane * 8;
    __builtin_nontemporal_store(a0, reinterpret_cast<vfloat4*>(orow));
    __builtin_nontemporal_store(a1, reinterpret_cast<vfloat4*>(orow) + 1);
}

extern "C" void kernel_launch(void* const* d_in, const int* in_sizes, int n_in,
                              void* d_out, int out_size, void* d_ws, size_t ws_size,
                              hipStream_t stream) {
    const int*   subnode_ids  = (const int*)d_in[0];
    const int*   mask_batch   = (const int*)d_in[1];
    const int*   mask_node    = (const int*)d_in[2];
    const int*   mask_subnode = (const int*)d_in[3];
    const float* mask_values  = (const float*)d_in[4];
    const float* emb_table    = (const float*)d_in[5];
    float*       out          = (float*)d_out;

    // ws layout: emb16[VOCAB*D halves, 12.86 MB] | binMem[NBIN*BCAP u64, 12.6 MB]
    //          | binCnt[NBIN*CSTRIDE, 128 KB] | ovfn[1] pad[63] | ovf[OVF_MAX]
    unsigned short* emb16 = (unsigned short*)d_ws;
    u64* binMem = (u64*)(emb16 + (size_t)VOCABq * Dq + 64 /*align pad*/);
    int* binCnt = (int*)(binMem + (size_t)NBIN * BCAP);
    int* ovfn   = binCnt + NBIN * CSTRIDE;
    int* ovf    = ovfn + 64;

    (void)hipMemsetAsync(binCnt, 0, (NBIN * CSTRIDE + 64) * sizeof(int), stream);

    const int NQUAD = (VOCABq * Dq) / 4;
    const int NBCAST = (NQUAD + BTPB * CAST_QPT - 1) / (BTPB * CAST_QPT);  // 393
    cast_bin_kernel<<<NBBIN + NBCAST, BTPB, 0, stream>>>(
        emb_table, emb16, subnode_ids, mask_batch, mask_node, mask_subnode,
        mask_values, binCnt, binMem, ovfn, ovf);
    pool_kernel<<<NBIN, 256, 0, stream>>>(
        emb16, binCnt, binMem, subnode_ids, mask_batch, mask_node, mask_subnode,
        mask_values, ovfn, ovf, out);
}

// Round 2
// 131.265 us; speedup vs baseline: 1.1289x; 1.1289x over previous
//
#include <hip/hip_runtime.h>
#include <hip/hip_fp16.h>

#define Bq 16
#define Nq 2048
#define Sq 4096
#define Dq 128
#define VOCABq 50257
#define NNZq 1048576
#define ROWS (Bq * Nq)   // 32768
#define NBIN 512         // coarse bins of 64 rows
#define RPB 64           // rows per bin
#define BCAP 2432        // bin capacity (mean 2048, sd ~45 -> +8.5 sigma)
#define OVF_MAX 65536
#define BTPB 1024        // bin kernel threads
#define BEPT 4           // bin entries/thread
#define ENT (BTPB * BEPT)       // 4096 entries per bin block
#define NBBLK (NNZq / ENT)      // 256 bin blocks
#define CSTRIDE 16       // binCnt padding: 1 counter per 64B line
#define PTPB 1024        // pool threads (64 row-groups x 16 lanes)
#define NKEY 256         // pool sort keys: 4 token-quarters x 64 rows

typedef unsigned long long u64;
typedef float vfloat4 __attribute__((ext_vector_type(4)));
typedef unsigned short vushort4 __attribute__((ext_vector_type(4)));
typedef unsigned short vushort8 __attribute__((ext_vector_type(8)));

// ---------- Pass 0: cast emb fp32->fp16; block 0 also zeroes counters ----------
__global__ __launch_bounds__(256) void cast_kernel(
    const float* __restrict__ emb, unsigned short* __restrict__ emb16,
    int* __restrict__ binCnt)   // zeroes binCnt[NBIN*CSTRIDE] + ovfn pad
{
    if (blockIdx.x == 0) {
        for (int i = threadIdx.x; i < NBIN * CSTRIDE + 64; i += 256) binCnt[i] = 0;
    }
    const int NQUAD = (VOCABq * Dq) / 4;  // 1,608,224
    int i = blockIdx.x * 256 + threadIdx.x;
    if (i >= NQUAD) return;
    vfloat4 f = reinterpret_cast<const vfloat4*>(emb)[i];
    vushort4 h;
    h.x = __half_as_ushort(__float2half_rn(f.x));
    h.y = __half_as_ushort(__float2half_rn(f.y));
    h.z = __half_as_ushort(__float2half_rn(f.z));
    h.w = __half_as_ushort(__float2half_rn(f.w));
    __builtin_nontemporal_store(h, reinterpret_cast<vushort4*>(emb16) + i);
}

// ---------- Pass A: radix scatter with in-LDS bin sort -> coalesced writes ----------
// 4096 entries/block over 512 bins => ~8-entry runs per bin. Entries are sorted
// by bin in LDS, then written out in sorted order: consecutive lanes hit
// consecutive binMem addresses (full 64B lines instead of 8B partial lines).
__global__ __launch_bounds__(BTPB) void bin_kernel(
    const int* __restrict__ subnode_ids,   // [B,S]
    const int* __restrict__ mb,            // [NNZ]
    const int* __restrict__ mn,            // [NNZ]
    const int* __restrict__ ms,            // [NNZ]
    const float* __restrict__ mv,          // [NNZ]
    int* __restrict__ binCnt,              // [NBIN*CSTRIDE] (zeroed)
    u64* __restrict__ binMem,              // [NBIN*BCAP] packed entries
    int* __restrict__ ovfn,                // overflow counter (zeroed)
    int* __restrict__ ovf)                 // overflow nz list
{
    __shared__ int hist[NBIN];     // per-block bin counts
    __shared__ int lstart[NBIN];   // local exclusive prefix
    __shared__ int baseG[NBIN];    // global base per bin
    __shared__ int waveSum[8];
    __shared__ u64 spk[ENT];       // 32 KB sorted packed entries
    __shared__ int sdst[ENT];      // 16 KB global destinations

    int t = threadIdx.x;
    if (t < NBIN) hist[t] = 0;
    __syncthreads();

    int blockBase = blockIdx.x * ENT;
    int g[BEPT], rank[BEPT];
    u64 pk[BEPT];
    #pragma unroll
    for (int k = 0; k < BEPT; k++) {       // coalesced NT index loads + L2 token gather
        int i   = blockBase + k * BTPB + t;
        int b   = __builtin_nontemporal_load(mb + i);
        int row = b * Nq + __builtin_nontemporal_load(mn + i);
        int s   = __builtin_nontemporal_load(ms + i);
        float v = __builtin_nontemporal_load(mv + i);
        int tok = subnode_ids[b * Sq + s];
        g[k]  = row >> 6;                  // bin of 64 rows
        pk[k] = ((u64)(unsigned)__float_as_int(v) << 32)
              | ((u64)(row & 63) << 16)
              | (unsigned)tok;             // tok < 65536 fits 16 bits
        rank[k] = atomicAdd(&hist[g[k]], 1);
    }
    __syncthreads();

    // local exclusive prefix over 512 bins (8 waves) + global base atomics
    int lane = t & 63, wid = t >> 6;
    int v  = (t < NBIN) ? hist[t] : 0;
    int vi = v;
    #pragma unroll
    for (int d = 1; d < 64; d <<= 1) {
        int w = __shfl_up(vi, d, 64);
        if (lane >= d) vi += w;
    }
    if (t < NBIN && lane == 63) waveSum[wid] = vi;
    if (t < NBIN && v) baseG[t] = atomicAdd(&binCnt[t * CSTRIDE], v);
    __syncthreads();
    if (t == 0) {
        int s = 0;
        #pragma unroll
        for (int w = 0; w < NBIN / 64; w++) { int x = waveSum[w]; waveSum[w] = s; s += x; }
    }
    __syncthreads();
    if (t < NBIN) lstart[t] = vi - v + waveSum[wid];
    __syncthreads();

    // scatter into LDS sorted by (bin, rank); record global destination
    #pragma unroll
    for (int k = 0; k < BEPT; k++) {
        int b = g[k], r = rank[k];
        int p = lstart[b] + r;
        spk[p] = pk[k];
        int pos = baseG[b] + r;
        if (pos < BCAP) {
            sdst[p] = b * BCAP + pos;
        } else {
            sdst[p] = -1;
            int o = atomicAdd(ovfn, 1);
            if (o < OVF_MAX) ovf[o] = blockBase + k * BTPB + t;
        }
    }
    __syncthreads();

    // coalesced write-out: consecutive lanes -> consecutive addresses within runs
    #pragma unroll
    for (int k = 0; k < BEPT; k++) {
        int p = t + k * BTPB;
        int d = sdst[p];
        if (d >= 0) binMem[d] = spk[p];
    }
}

// ---------- Pass B: in-LDS sort by (token-quarter, row) + phased pool ----------
// One 1024-thread block per bin (64 rows). Sort key = (tok>>14)<<6 | row_local:
// block processes entries in 4 token-range phases (~3.2MB fp16 table slice,
// L2-resident across co-resident blocks). 64 groups of 16 lanes; group g owns
// row g (lane = 16B ushort8 slice); acc in fp32 regs; one NT 512B store/row.
// Rare overflow entries folded in before the store (scan only if *ovfn > 0).
__global__ __launch_bounds__(PTPB) void pool_kernel(
    const unsigned short* __restrict__ emb16,  // [VOCAB,D] fp16
    const int* __restrict__ binCnt,            // [NBIN*CSTRIDE]
    const u64* __restrict__ binMem,            // [NBIN*BCAP]
    const int* __restrict__ subnode_ids,
    const int* __restrict__ mb, const int* __restrict__ mn,
    const int* __restrict__ ms, const float* __restrict__ mv,
    const int* __restrict__ ovfn, const int* __restrict__ ovf,
    float* __restrict__ out)                   // [ROWS,D]
{
    __shared__ u64 ebuf[BCAP];          // 19 KB sorted entries
    __shared__ int hist[NKEY];
    __shared__ int start[NKEY + 1];
    __shared__ int cursor[NKEY];
    __shared__ int waveSum[4];

    int t   = threadIdx.x;
    int bin = blockIdx.x;
    if (t < NKEY) hist[t] = 0;
    __syncthreads();

    int n = min(binCnt[bin * CSTRIDE], BCAP);
    const u64* bm = binMem + (size_t)bin * BCAP;

    // stage entries (<=3 per thread) + histogram 256 keys
    u64 myPk[3];
    int myKey[3], myCnt = 0;
    for (int e = t; e < n; e += PTPB) {
        u64 pk  = bm[e];
        int tok = (int)(pk & 0xFFFF);
        int key = ((tok >> 14) << 6) | (int)((pk >> 16) & 63);
        myPk[myCnt] = pk; myKey[myCnt] = key; myCnt++;
        atomicAdd(&hist[key], 1);
    }
    __syncthreads();

    // exclusive prefix over 256 keys (4 waves + cross-wave fixup)
    int lane = t & 63, wid = t >> 6;
    int v  = (t < NKEY) ? hist[t] : 0;
    int vi = v;
    #pragma unroll
    for (int d = 1; d < 64; d <<= 1) {
        int w = __shfl_up(vi, d, 64);
        if (lane >= d) vi += w;
    }
    if (t < NKEY && lane == 63) waveSum[wid] = vi;
    __syncthreads();
    if (t == 0) {
        int s = 0;
        #pragma unroll
        for (int w = 0; w < NKEY / 64; w++) { int x = waveSum[w]; waveSum[w] = s; s += x; }
    }
    __syncthreads();
    if (t < NKEY) {
        int ex = vi - v + waveSum[wid];
        start[t] = ex;
        cursor[t] = ex;
        if (t == NKEY - 1) start[NKEY] = ex + v;
    }
    __syncthreads();
    for (int k = 0; k < myCnt; k++) {
        int p = atomicAdd(&cursor[myKey[k]], 1);
        ebuf[p] = myPk[k];
    }
    __syncthreads();

    // pool: group g (16 lanes) owns row g; 4 token-quarter phases
    int g    = t >> 4;       // 0..63
    int lane16 = t & 15;
    vfloat4 a0 = {0.f, 0.f, 0.f, 0.f};
    vfloat4 a1 = {0.f, 0.f, 0.f, 0.f};
    #pragma unroll
    for (int q = 0; q < 4; q++) {
        int s0 = start[q * 64 + g], s1 = start[q * 64 + g + 1];
        int k = s0;
        for (; k + 8 <= s1; k += 8) {      // 8 independent 256B row-gathers in flight
            int   tk[8];
            float vv[8];
            #pragma unroll
            for (int u = 0; u < 8; u++) {
                u64 pk = ebuf[k + u];      // same addr within group -> broadcast
                tk[u] = (int)(pk & 0xFFFF);
                vv[u] = __int_as_float((int)(pk >> 32));
            }
            vushort8 e[8];
            #pragma unroll
            for (int u = 0; u < 8; u++)
                e[u] = reinterpret_cast<const vushort8*>(emb16 + (size_t)tk[u] * Dq)[lane16];
            #pragma unroll
            for (int u = 0; u < 8; u++) {
                a0.x += __half2float(__ushort_as_half(e[u][0])) * vv[u];
                a0.y += __half2float(__ushort_as_half(e[u][1])) * vv[u];
                a0.z += __half2float(__ushort_as_half(e[u][2])) * vv[u];
                a0.w += __half2float(__ushort_as_half(e[u][3])) * vv[u];
                a1.x += __half2float(__ushort_as_half(e[u][4])) * vv[u];
                a1.y += __half2float(__ushort_as_half(e[u][5])) * vv[u];
                a1.z += __half2float(__ushort_as_half(e[u][6])) * vv[u];
                a1.w += __half2float(__ushort_as_half(e[u][7])) * vv[u];
            }
        }
        for (; k < s1; k++) {
            u64 pk = ebuf[k];
            int   tok = (int)(pk & 0xFFFF);
            float v2  = __int_as_float((int)(pk >> 32));
            vushort8 e = reinterpret_cast<const vushort8*>(emb16 + (size_t)tok * Dq)[lane16];
            a0.x += __half2float(__ushort_as_half(e[0])) * v2;
            a0.y += __half2float(__ushort_as_half(e[1])) * v2;
            a0.z += __half2float(__ushort_as_half(e[2])) * v2;
            a0.w += __half2float(__ushort_as_half(e[3])) * v2;
            a1.x += __half2float(__ushort_as_half(e[4])) * v2;
            a1.y += __half2float(__ushort_as_half(e[5])) * v2;
            a1.z += __half2float(__ushort_as_half(e[6])) * v2;
            a1.w += __half2float(__ushort_as_half(e[7])) * v2;
        }
    }

    // rare overflow fold-in (usually *ovfn == 0)
    int nov = min(*ovfn, OVF_MAX);
    for (int e2 = 0; e2 < nov; e2++) {
        int i = ovf[e2];
        int b = mb[i];
        int row = b * Nq + mn[i];
        if ((row >> 6) != bin || (row & 63) != g) continue;
        int tok = subnode_ids[b * Sq + ms[i]];
        float v2 = mv[i];
        vushort8 e = reinterpret_cast<const vushort8*>(emb16 + (size_t)tok * Dq)[lane16];
        a0.x += __half2float(__ushort_as_half(e[0])) * v2;
        a0.y += __half2float(__ushort_as_half(e[1])) * v2;
        a0.z += __half2float(__ushort_as_half(e[2])) * v2;
        a0.w += __half2float(__ushort_as_half(e[3])) * v2;
        a1.x += __half2float(__ushort_as_half(e[4])) * v2;
        a1.y += __half2float(__ushort_as_half(e[5])) * v2;
        a1.z += __half2float(__ushort_as_half(e[6])) * v2;
        a1.w += __half2float(__ushort_as_half(e[7])) * v2;
    }

    float* orow = out + ((size_t)bin * RPB + g) * Dq + lane16 * 8;
    __builtin_nontemporal_store(a0, reinterpret_cast<vfloat4*>(orow));
    __builtin_nontemporal_store(a1, reinterpret_cast<vfloat4*>(orow) + 1);
}

extern "C" void kernel_launch(void* const* d_in, const int* in_sizes, int n_in,
                              void* d_out, int out_size, void* d_ws, size_t ws_size,
                              hipStream_t stream) {
    const int*   subnode_ids  = (const int*)d_in[0];
    const int*   mask_batch   = (const int*)d_in[1];
    const int*   mask_node    = (const int*)d_in[2];
    const int*   mask_subnode = (const int*)d_in[3];
    const float* mask_values  = (const float*)d_in[4];
    const float* emb_table    = (const float*)d_in[5];
    float*       out          = (float*)d_out;

    // ws layout: emb16[VOCAB*D halves, 12.86 MB] | binMem[NBIN*BCAP u64, 9.96 MB]
    //          | binCnt[NBIN*CSTRIDE, 32 KB] | ovfn[1] pad[63] | ovf[OVF_MAX]
    unsigned short* emb16 = (unsigned short*)d_ws;
    u64* binMem = (u64*)(emb16 + (size_t)VOCABq * Dq + 64 /*align pad*/);
    int* binCnt = (int*)(binMem + (size_t)NBIN * BCAP);
    int* ovfn   = binCnt + NBIN * CSTRIDE;
    int* ovf    = ovfn + 64;

    const int NQUAD = (VOCABq * Dq) / 4;
    cast_kernel<<<(NQUAD + 255) / 256, 256, 0, stream>>>(emb_table, emb16, binCnt);
    bin_kernel<<<NBBLK, BTPB, 0, stream>>>(
        subnode_ids, mask_batch, mask_node, mask_subnode, mask_values,
        binCnt, binMem, ovfn, ovf);
    pool_kernel<<<NBIN, PTPB, 0, stream>>>(
        emb16, binCnt, binMem, subnode_ids, mask_batch, mask_node, mask_subnode,
        mask_values, ovfn, ovf, out);
}